// Round 10
// baseline (488.844 us; speedup 1.0000x reference)
//
#include <hip/hip_runtime.h>
#include <math.h>

#define DD 8
#define HH 4
#define EE 4
#define NLAYER 4
#define BB 4
#define SS 20
#define IMM 64

static constexpr int NPOS = BB * SS * IMM * IMM;          // 327680
static constexpr size_t ZBYTES = (size_t)NPOS * DD * 4;   // 10485760

// ---------------------------------------------------------------------------
__global__ __launch_bounds__(256)
void emb_kernel(const float* __restrict__ x, const float* __restrict__ conv_w,
                const float* __restrict__ pos_s, const float* __restrict__ pos_h,
                const float* __restrict__ pos_w, float* __restrict__ xt) {
    int idx = blockIdx.x * 256 + threadIdx.x;
    if (idx >= NPOS) return;
    int j = idx & 63;
    int i = (idx >> 6) & 63;
    int s = (idx >> 12) % SS;
    float xv = x[idx];
    float o[8];
#pragma unroll
    for (int d = 0; d < 8; ++d) {
        float v = xv * conv_w[d];
        v = v > 0.f ? v : 0.f;
        o[d] = v + pos_s[s * 8 + d] + pos_h[d * 64 + i] + pos_w[d * 64 + j];
    }
    float4* dst = (float4*)(xt + (size_t)idx * 8);
    dst[0] = make_float4(o[0], o[1], o[2], o[3]);
    dst[1] = make_float4(o[4], o[5], o[6], o[7]);
}

__device__ __forceinline__ float dot4(float4 a, float4 b) {
    return fmaf(a.w, b.w, fmaf(a.z, b.z, fmaf(a.y, b.y, a.x * b.x)));
}
// dot with initial accumulator (folds the -B2 bias into the fma chain)
__device__ __forceinline__ float dot4i(float4 a, float4 b, float c0) {
    return fmaf(a.x, b.x, fmaf(a.y, b.y, fmaf(a.z, b.z, fmaf(a.w, b.w, c0))));
}

// ---------------------------------------------------------------------------
// Axis attention, single-pass softmax with a-priori Cauchy-Schwarz bound
// (p = exp2(q'.k - B2), B2 = |q'|*max|k| in log2 units). RPT query rows per
// thread: each K/V ds_read_b128 pair is amortized over RPT rows (this kernel
// is LDS-issue-bound: 128 ds instr/wave at RPT=2 ~ 26us/CU vs 12us VALU).
// WPE = min waves per EU for __launch_bounds__ (8 -> VGPR<=64 when VGPRs
// bind occupancy; 4 -> VGPR<=128 when LDS binds it anyway).
template <int L, int RPT, int LINES, bool ACCUM, int STG, int WPE>
__global__ __launch_bounds__(HH * (L / RPT) * LINES, WPE)
void attn_kernel(const float* __restrict__ src, float* __restrict__ dst,
                 const float* __restrict__ Wq, const float* __restrict__ Wkv,
                 const float* __restrict__ Wo, const float* __restrict__ bo,
                 int m0, int c1, int m1, int stride) {
    constexpr int RG = L / RPT;          // row-groups per (line, head)
    constexpr int TL = HH * RG;          // threads per line
    constexpr int NT = TL * LINES;       // block size
    constexpr int LL = L * LINES;

    __shared__ float4 zl4[2][LL];        // z line, 2 quads per position
    __shared__ float4 kv4[LL][8];        // quads 0..3 = K heads, 4..7 = V heads
    __shared__ float4 olT4[HH][LL];      // attention out, head-major
    __shared__ float4 wq4[8][4];         // wq4[d][h]
    __shared__ float4 wkv4[8][8];        // wkv4[d][c]
    __shared__ float4 woq4[16][2];       // woq4[c][dq] = Wo[c][4dq..4dq+3]
    __shared__ float4 bo4_s[2];
    __shared__ float  Mh2[LINES][HH];    // max |k|^2 per (line, head)

    const int t = threadIdx.x;
    if (t < 32) wq4[t >> 2][t & 3]  = *(const float4*)(Wq  + t * 4);
    if (t < 64) wkv4[t >> 3][t & 7] = *(const float4*)(Wkv + t * 4);
    if (t < 32) woq4[t >> 1][t & 1] = *(const float4*)(Wo  + t * 4);
    if (t < 2)  bo4_s[t]            = *(const float4*)(bo  + t * 4);
    if (t < LINES * HH) Mh2[t / HH][t % HH] = 0.f;

    auto line_base = [&](int ln) -> size_t {
        int lid = blockIdx.x * LINES + ln;
        int u0 = lid & 63;
        int rest = lid >> 6;
        int u1 = rest % c1;
        int b  = rest / c1;
        return (size_t)b * 655360 + (size_t)u1 * m1 + (size_t)u0 * m0;
    };

    // ---- stage z ----
    for (int idx = t; idx < LL * 2; idx += NT) {
        int q, ln, p;
        if (STG == 1) { q = idx & 1; int r = idx >> 1; ln = r % LINES; p = r / LINES; }
        else          { q = idx & 1; int r = idx >> 1; ln = r / L;     p = r % L;     }
        zl4[q][ln * L + p] = *(const float4*)(src + line_base(ln) + (size_t)p * stride + q * 4);
    }
    __syncthreads();

    // ---- K,V projection (c fixed per thread); track max |k|^2 per head ----
    {
        const int c = t & 7;
        float4 wc[8];
#pragma unroll
        for (int d = 0; d < 8; ++d) wc[d] = wkv4[d][c];
        for (int idx = t; idx < LL * 8; idx += NT) {
            int lp = idx >> 3;
            float4 z0 = zl4[0][lp], z1 = zl4[1][lp];
            const float zs[8] = {z0.x, z0.y, z0.z, z0.w, z1.x, z1.y, z1.z, z1.w};
            float4 acc = make_float4(0.f, 0.f, 0.f, 0.f);
#pragma unroll
            for (int d = 0; d < 8; ++d) {
                acc.x += zs[d] * wc[d].x; acc.y += zs[d] * wc[d].y;
                acc.z += zs[d] * wc[d].z; acc.w += zs[d] * wc[d].w;
            }
            kv4[lp][c] = acc;
            if (c < 4)   // K quad: c == head index
                atomicMax((int*)&Mh2[lp / L][c], __float_as_int(dot4(acc, acc)));
        }
    }
    __syncthreads();

    // ---- attention: thread = (line, head, RPT rows); single pass ----
    {
        const int ln = t / TL;
        const int r  = t % TL;
        const int h  = r / RG;
        const int rg = r % RG;
        const int jb = ln * L;
        const int i0 = rg * RPT;
        const float SC = 0.5f * 1.44269504f;   // E^-0.5 * log2(e)

        float4 q[RPT];
        float nB2[RPT];
        const float mh2 = Mh2[ln][h];
#pragma unroll
        for (int k = 0; k < RPT; ++k) {
            float4 z0 = zl4[0][jb + i0 + k], z1 = zl4[1][jb + i0 + k];
            const float zs[8] = {z0.x, z0.y, z0.z, z0.w, z1.x, z1.y, z1.z, z1.w};
            float4 acc = make_float4(0.f, 0.f, 0.f, 0.f);
#pragma unroll
            for (int d = 0; d < 8; ++d) {
                float4 w = wq4[d][h];
                acc.x += zs[d] * w.x; acc.y += zs[d] * w.y;
                acc.z += zs[d] * w.z; acc.w += zs[d] * w.w;
            }
            q[k] = make_float4(acc.x * SC, acc.y * SC, acc.z * SC, acc.w * SC);
            nB2[k] = -sqrtf(dot4(q[k], q[k]) * mh2);   // -(|q'| max|k|), log2 units
        }

        float s[RPT];
        float4 o[RPT];
#pragma unroll
        for (int k = 0; k < RPT; ++k) { s[k] = 0.f; o[k] = make_float4(0.f, 0.f, 0.f, 0.f); }
#pragma unroll 4
        for (int j = 0; j < L; ++j) {
            float4 kk = kv4[jb + j][h];
            float4 vv = kv4[jb + j][4 + h];
#pragma unroll
            for (int k = 0; k < RPT; ++k) {
                float p = __builtin_amdgcn_exp2f(dot4i(q[k], kk, nB2[k]));
                s[k] += p;
                o[k].x += p * vv.x; o[k].y += p * vv.y;
                o[k].z += p * vv.z; o[k].w += p * vv.w;
            }
        }
#pragma unroll
        for (int k = 0; k < RPT; ++k) {
            const float inv = 1.f / fmaxf(s[k], 1e-37f);
            olT4[h][jb + i0 + k] =
                make_float4(o[k].x * inv, o[k].y * inv, o[k].z * inv, o[k].w * inv);
        }
    }
    __syncthreads();

    // ---- output projection, float4 per (position, d-quad) ----
    {
        const int dq = t & 1;
        float4 wr[16];
#pragma unroll
        for (int c = 0; c < 16; ++c) wr[c] = woq4[c][dq];
        float4 bo4 = bo4_s[dq];
        for (int idx = t; idx < LL * 2; idx += NT) {
            int ln, p;
            if (STG == 1) { int r = idx >> 1; ln = r % LINES; p = r / LINES; }
            else          { int r = idx >> 1; ln = r / L;     p = r % L;     }
            int lp = ln * L + p;
            float4 o0 = olT4[0][lp], o1 = olT4[1][lp];
            float4 o2 = olT4[2][lp], o3 = olT4[3][lp];
            const float oc[16] = {o0.x, o0.y, o0.z, o0.w, o1.x, o1.y, o1.z, o1.w,
                                  o2.x, o2.y, o2.z, o2.w, o3.x, o3.y, o3.z, o3.w};
            float4 acc = bo4;
#pragma unroll
            for (int c = 0; c < 16; ++c) {
                acc.x += oc[c] * wr[c].x; acc.y += oc[c] * wr[c].y;
                acc.z += oc[c] * wr[c].z; acc.w += oc[c] * wr[c].w;
            }
            float* gp = dst + line_base(ln) + (size_t)p * stride + dq * 4;
            if (ACCUM) {
                float4 old = *(const float4*)gp;
                acc.x += old.x; acc.y += old.y; acc.z += old.z; acc.w += old.w;
            }
            *(float4*)gp = acc;
        }
    }
}

// ---------------------------------------------------------------------------
__global__ __launch_bounds__(256)
void reduce_kernel(const float* __restrict__ z, const float* __restrict__ xt,
                   const float* __restrict__ Wc, float* __restrict__ accum) {
    const int b  = blockIdx.x >> 4;
    const int ij = ((blockIdx.x & 15) << 8) + threadIdx.x;
    float4 m0 = make_float4(-1e30f, -1e30f, -1e30f, -1e30f);
    float4 m1 = m0;
    for (int s = 0; s < SS; ++s) {
        size_t off = (((size_t)(b * SS + s)) * 4096 + ij) * 8;
        float4 a0 = *(const float4*)(z + off);
        float4 a1 = *(const float4*)(z + off + 4);
        float4 c0 = *(const float4*)(xt + off);
        float4 c1 = *(const float4*)(xt + off + 4);
        m0.x = fmaxf(m0.x, a0.x + c0.x); m0.y = fmaxf(m0.y, a0.y + c0.y);
        m0.z = fmaxf(m0.z, a0.z + c0.z); m0.w = fmaxf(m0.w, a0.w + c0.w);
        m1.x = fmaxf(m1.x, a1.x + c1.x); m1.y = fmaxf(m1.y, a1.y + c1.y);
        m1.z = fmaxf(m1.z, a1.z + c1.z); m1.w = fmaxf(m1.w, a1.w + c1.w);
    }
    float partial =
        m0.x * Wc[0 * 4096 + ij] + m0.y * Wc[1 * 4096 + ij] +
        m0.z * Wc[2 * 4096 + ij] + m0.w * Wc[3 * 4096 + ij] +
        m1.x * Wc[4 * 4096 + ij] + m1.y * Wc[5 * 4096 + ij] +
        m1.z * Wc[6 * 4096 + ij] + m1.w * Wc[7 * 4096 + ij];

    __shared__ float red[256];
    red[threadIdx.x] = partial;
    __syncthreads();
#pragma unroll
    for (int off = 128; off > 0; off >>= 1) {
        if (threadIdx.x < off) red[threadIdx.x] += red[threadIdx.x + off];
        __syncthreads();
    }
    if (threadIdx.x == 0) atomicAdd(&accum[b], red[0]);
}

__global__ void final_kernel(const float* __restrict__ accum,
                             const float* __restrict__ bc,
                             float* __restrict__ out) {
    int b = threadIdx.x;
    if (b < BB) out[b] = 1.f / (1.f + expf(-(accum[b] + bc[0])));
}

// ---------------------------------------------------------------------------
extern "C" void kernel_launch(void* const* d_in, const int* in_sizes, int n_in,
                              void* d_out, int out_size, void* d_ws, size_t ws_size,
                              hipStream_t stream) {
    const float* x      = (const float*)d_in[0];
    const float* conv_w = (const float*)d_in[1];
    const float* pos_s  = (const float*)d_in[2];
    const float* pos_h  = (const float*)d_in[3];
    const float* pos_w  = (const float*)d_in[4];
    const float* Wq     = (const float*)d_in[5];
    const float* Wkv    = (const float*)d_in[6];
    const float* Wo     = (const float*)d_in[7];
    const float* bo     = (const float*)d_in[8];
    const float* Wc     = (const float*)d_in[9];
    const float* bc     = (const float*)d_in[10];
    float* out = (float*)d_out;

    char* ws = (char*)d_ws;
    float* xt    = (float*)(ws);
    float* zA    = (float*)(ws + ZBYTES);
    float* zB    = (float*)(ws + 2 * ZBYTES);
    float* accum = (float*)(ws + 3 * ZBYTES);

    emb_kernel<<<NPOS / 256, 256, 0, stream>>>(x, conv_w, pos_s, pos_h, pos_w, xt);

    const float* cur = xt;
    float* bufs[2] = {zA, zB};
    int w = 0;
    for (int l = 0; l < NLAYER; ++l) {
        float* dstp = bufs[w];
        const float* wq0  = Wq  + (size_t)(l * 3 + 0) * 128;
        const float* wkv0 = Wkv + (size_t)(l * 3 + 0) * 256;
        const float* wo0  = Wo  + (size_t)(l * 3 + 0) * 128;
        const float* bo0  = bo  + (size_t)(l * 3 + 0) * 8;
        // a=0: attend over s (L=20), RPT=2, 8 lines/block, 320 thr, VGPR<=64
        attn_kernel<SS, 2, 8, false, 1, 8><<<BB * IMM * IMM / 8, HH * (SS / 2) * 8, 0, stream>>>(
            cur, dstp, wq0, wkv0, wo0, bo0, 8, 64, 512, 32768);
        // a=1: attend over i (L=64), RPT=4, 2 lines/block, 128 thr, VGPR<=128
        attn_kernel<IMM, 4, 2, true, 1, 4><<<BB * SS * IMM / 2, HH * (IMM / 4) * 2, 0, stream>>>(
            cur, dstp, wq0 + 128, wkv0 + 256, wo0 + 128, bo0 + 8, 8, 20, 32768, 512);
        // a=2: attend over j (L=64), RPT=4, position-fastest staging
        attn_kernel<IMM, 4, 2, true, 0, 4><<<BB * SS * IMM / 2, HH * (IMM / 4) * 2, 0, stream>>>(
            cur, dstp, wq0 + 256, wkv0 + 512, wo0 + 256, bo0 + 16, 512, 20, 32768, 8);
        cur = dstp;
        w ^= 1;
    }

    hipMemsetAsync(accum, 0, BB * sizeof(float), stream);
    reduce_kernel<<<BB * 16, 256, 0, stream>>>(cur, xt, Wc, accum);
    final_kernel<<<1, 64, 0, stream>>>(accum, bc, out);
}

// Round 11
// 455.650 us; speedup vs baseline: 1.0728x; 1.0728x over previous
//
#include <hip/hip_runtime.h>
#include <math.h>

#define DD 8
#define HH 4
#define EE 4
#define NLAYER 4
#define BB 4
#define SS 20
#define IMM 64

static constexpr int NPOS = BB * SS * IMM * IMM;          // 327680
static constexpr size_t ZBYTES = (size_t)NPOS * DD * 4;   // 10485760

// ---------------------------------------------------------------------------
__global__ __launch_bounds__(256)
void emb_kernel(const float* __restrict__ x, const float* __restrict__ conv_w,
                const float* __restrict__ pos_s, const float* __restrict__ pos_h,
                const float* __restrict__ pos_w, float* __restrict__ xt) {
    int idx = blockIdx.x * 256 + threadIdx.x;
    if (idx >= NPOS) return;
    int j = idx & 63;
    int i = (idx >> 6) & 63;
    int s = (idx >> 12) % SS;
    float xv = x[idx];
    float o[8];
#pragma unroll
    for (int d = 0; d < 8; ++d) {
        float v = xv * conv_w[d];
        v = v > 0.f ? v : 0.f;
        o[d] = v + pos_s[s * 8 + d] + pos_h[d * 64 + i] + pos_w[d * 64 + j];
    }
    float4* dst = (float4*)(xt + (size_t)idx * 8);
    dst[0] = make_float4(o[0], o[1], o[2], o[3]);
    dst[1] = make_float4(o[4], o[5], o[6], o[7]);
}

__device__ __forceinline__ float dot4(float4 a, float4 b) {
    return fmaf(a.w, b.w, fmaf(a.z, b.z, fmaf(a.y, b.y, a.x * b.x)));
}
// dot with initial accumulator (folds the -B2 bias into the fma chain)
__device__ __forceinline__ float dot4i(float4 a, float4 b, float c0) {
    return fmaf(a.x, b.x, fmaf(a.y, b.y, fmaf(a.z, b.z, fmaf(a.w, b.w, c0))));
}

// ---------------------------------------------------------------------------
// Axis attention, single-pass softmax with a-priori Cauchy-Schwarz bound
// (p = exp2(q'.k - B2), B2 = |q'|*max|k| in log2 units). RPT=2 query rows per
// thread. Kernel is global-latency bound -> levers: (a) zl4/olT4 share one
// LDS pool (zl4 dead after q-setup; barrier guards the transition) to fit
// more blocks/CU; (b) ACCUM dst read issued at kernel START (1 float4/thr),
// consumed in the epilogue -- rmw latency hidden under the body.
template <int L, int RPT, int LINES, bool ACCUM, int STG, int WPE>
__global__ __launch_bounds__(HH * (L / RPT) * LINES, WPE)
void attn_kernel(const float* __restrict__ src, float* __restrict__ dst,
                 const float* __restrict__ Wq, const float* __restrict__ Wkv,
                 const float* __restrict__ Wo, const float* __restrict__ bo,
                 int m0, int c1, int m1, int stride) {
    constexpr int RG = L / RPT;          // row-groups per (line, head)
    constexpr int TL = HH * RG;          // threads per line
    constexpr int NT = TL * LINES;       // block size
    constexpr int LL = L * LINES;

    // pool: phases 1-2 hold zl4[2][LL]; phase 3+ holds olT4[HH][LL]
    __shared__ float4 pool4[HH * LL];
    __shared__ float4 kv4[LL][8];        // quads 0..3 = K heads, 4..7 = V heads
    __shared__ float4 wq4[8][4];         // wq4[d][h]
    __shared__ float4 wkv4[8][8];        // wkv4[d][c]
    __shared__ float4 woq4[16][2];       // woq4[c][dq] = Wo[c][4dq..4dq+3]
    __shared__ float4 bo4_s[2];
    __shared__ float  Mh2[LINES][HH];    // max |k|^2 per (line, head)

#define ZL4(qq, lp)  pool4[(qq) * LL + (lp)]
#define OLT4(hh, lp) pool4[(hh) * LL + (lp)]

    const int t = threadIdx.x;
    if (t < 32) wq4[t >> 2][t & 3]  = *(const float4*)(Wq  + t * 4);
    if (t < 64) wkv4[t >> 3][t & 7] = *(const float4*)(Wkv + t * 4);
    if (t < 32) woq4[t >> 1][t & 1] = *(const float4*)(Wo  + t * 4);
    if (t < 2)  bo4_s[t]            = *(const float4*)(bo  + t * 4);
    if (t < LINES * HH) Mh2[t / HH][t % HH] = 0.f;

    auto line_base = [&](int ln) -> size_t {
        int lid = blockIdx.x * LINES + ln;
        int u0 = lid & 63;
        int rest = lid >> 6;
        int u1 = rest % c1;
        int b  = rest / c1;
        return (size_t)b * 655360 + (size_t)u1 * m1 + (size_t)u0 * m0;
    };
    // (ln, p) mapping for the staging/output iteration order
    auto map_lp = [&](int idx, int& ln, int& p) {
        int r = idx >> 1;
        if (STG == 1) { ln = r % LINES; p = r / LINES; }
        else          { ln = r / L;     p = r % L;     }
    };

    // ---- stage z (issue first) ----
    for (int idx = t; idx < LL * 2; idx += NT) {
        int ln, p;
        map_lp(idx, ln, p);
        ZL4(idx & 1, ln * L + p) =
            *(const float4*)(src + line_base(ln) + (size_t)p * stride + (idx & 1) * 4);
    }

    // ---- early dst read for ACCUM (exactly one float4 per thread in all
    //      configs: LL*2 == NT). Latency hides under the kernel body. ----
    float4 dst_old = make_float4(0.f, 0.f, 0.f, 0.f);
    if (ACCUM && t < LL * 2) {
        int ln, p;
        map_lp(t, ln, p);
        dst_old = *(const float4*)(dst + line_base(ln) + (size_t)p * stride + (t & 1) * 4);
    }
    __syncthreads();

    // ---- K,V projection (c fixed per thread); track max |k|^2 per head ----
    {
        const int c = t & 7;
        float4 wc[8];
#pragma unroll
        for (int d = 0; d < 8; ++d) wc[d] = wkv4[d][c];
        for (int idx = t; idx < LL * 8; idx += NT) {
            int lp = idx >> 3;
            float4 z0 = ZL4(0, lp), z1 = ZL4(1, lp);
            const float zs[8] = {z0.x, z0.y, z0.z, z0.w, z1.x, z1.y, z1.z, z1.w};
            float4 acc = make_float4(0.f, 0.f, 0.f, 0.f);
#pragma unroll
            for (int d = 0; d < 8; ++d) {
                acc.x += zs[d] * wc[d].x; acc.y += zs[d] * wc[d].y;
                acc.z += zs[d] * wc[d].z; acc.w += zs[d] * wc[d].w;
            }
            kv4[lp][c] = acc;
            if (c < 4)   // K quad: c == head index
                atomicMax((int*)&Mh2[lp / L][c], __float_as_int(dot4(acc, acc)));
        }
    }
    __syncthreads();

    // ---- attention: thread = (line, head, RPT rows); single pass ----
    {
        const int ln = t / TL;
        const int r  = t % TL;
        const int h  = r / RG;
        const int rg = r % RG;
        const int jb = ln * L;
        const int i0 = rg * RPT;
        const float SC = 0.5f * 1.44269504f;   // E^-0.5 * log2(e)

        float4 q[RPT];
        float nB2[RPT];
        const float mh2 = Mh2[ln][h];
#pragma unroll
        for (int k = 0; k < RPT; ++k) {
            float4 z0 = ZL4(0, jb + i0 + k), z1 = ZL4(1, jb + i0 + k);
            const float zs[8] = {z0.x, z0.y, z0.z, z0.w, z1.x, z1.y, z1.z, z1.w};
            float4 acc = make_float4(0.f, 0.f, 0.f, 0.f);
#pragma unroll
            for (int d = 0; d < 8; ++d) {
                float4 w = wq4[d][h];
                acc.x += zs[d] * w.x; acc.y += zs[d] * w.y;
                acc.z += zs[d] * w.z; acc.w += zs[d] * w.w;
            }
            q[k] = make_float4(acc.x * SC, acc.y * SC, acc.z * SC, acc.w * SC);
            nB2[k] = -sqrtf(dot4(q[k], q[k]) * mh2);   // -(|q'| max|k|), log2 units
        }

        // pool transitions zl4 -> olT4: all zl4 reads above must complete
        __syncthreads();

        float s[RPT];
        float4 o[RPT];
#pragma unroll
        for (int k = 0; k < RPT; ++k) { s[k] = 0.f; o[k] = make_float4(0.f, 0.f, 0.f, 0.f); }
#pragma unroll 8
        for (int j = 0; j < L; ++j) {
            float4 kk = kv4[jb + j][h];
            float4 vv = kv4[jb + j][4 + h];
#pragma unroll
            for (int k = 0; k < RPT; ++k) {
                float p = __builtin_amdgcn_exp2f(dot4i(q[k], kk, nB2[k]));
                s[k] += p;
                o[k].x += p * vv.x; o[k].y += p * vv.y;
                o[k].z += p * vv.z; o[k].w += p * vv.w;
            }
        }
#pragma unroll
        for (int k = 0; k < RPT; ++k) {
            const float inv = 1.f / fmaxf(s[k], 1e-37f);
            OLT4(h, jb + i0 + k) =
                make_float4(o[k].x * inv, o[k].y * inv, o[k].z * inv, o[k].w * inv);
        }
    }
    __syncthreads();

    // ---- output projection, float4 per (position, d-quad) ----
    {
        const int dq = t & 1;
        float4 wr[16];
#pragma unroll
        for (int c = 0; c < 16; ++c) wr[c] = woq4[c][dq];
        float4 bo4 = bo4_s[dq];
        for (int idx = t; idx < LL * 2; idx += NT) {
            int ln, p;
            map_lp(idx, ln, p);
            int lp = ln * L + p;
            float4 o0 = OLT4(0, lp), o1 = OLT4(1, lp);
            float4 o2 = OLT4(2, lp), o3 = OLT4(3, lp);
            const float oc[16] = {o0.x, o0.y, o0.z, o0.w, o1.x, o1.y, o1.z, o1.w,
                                  o2.x, o2.y, o2.z, o2.w, o3.x, o3.y, o3.z, o3.w};
            float4 acc = bo4;
#pragma unroll
            for (int c = 0; c < 16; ++c) {
                acc.x += oc[c] * wr[c].x; acc.y += oc[c] * wr[c].y;
                acc.z += oc[c] * wr[c].z; acc.w += oc[c] * wr[c].w;
            }
            if (ACCUM) {
                if (idx == t) {   // single iteration in all configs
                    acc.x += dst_old.x; acc.y += dst_old.y;
                    acc.z += dst_old.z; acc.w += dst_old.w;
                } else {
                    float4 old = *(const float4*)(dst + line_base(ln) + (size_t)p * stride + dq * 4);
                    acc.x += old.x; acc.y += old.y; acc.z += old.z; acc.w += old.w;
                }
            }
            *(float4*)(dst + line_base(ln) + (size_t)p * stride + dq * 4) = acc;
        }
    }
#undef ZL4
#undef OLT4
}

// ---------------------------------------------------------------------------
__global__ __launch_bounds__(256)
void reduce_kernel(const float* __restrict__ z, const float* __restrict__ xt,
                   const float* __restrict__ Wc, float* __restrict__ accum) {
    const int b  = blockIdx.x >> 4;
    const int ij = ((blockIdx.x & 15) << 8) + threadIdx.x;
    float4 m0 = make_float4(-1e30f, -1e30f, -1e30f, -1e30f);
    float4 m1 = m0;
    for (int s = 0; s < SS; ++s) {
        size_t off = (((size_t)(b * SS + s)) * 4096 + ij) * 8;
        float4 a0 = *(const float4*)(z + off);
        float4 a1 = *(const float4*)(z + off + 4);
        float4 c0 = *(const float4*)(xt + off);
        float4 c1 = *(const float4*)(xt + off + 4);
        m0.x = fmaxf(m0.x, a0.x + c0.x); m0.y = fmaxf(m0.y, a0.y + c0.y);
        m0.z = fmaxf(m0.z, a0.z + c0.z); m0.w = fmaxf(m0.w, a0.w + c0.w);
        m1.x = fmaxf(m1.x, a1.x + c1.x); m1.y = fmaxf(m1.y, a1.y + c1.y);
        m1.z = fmaxf(m1.z, a1.z + c1.z); m1.w = fmaxf(m1.w, a1.w + c1.w);
    }
    float partial =
        m0.x * Wc[0 * 4096 + ij] + m0.y * Wc[1 * 4096 + ij] +
        m0.z * Wc[2 * 4096 + ij] + m0.w * Wc[3 * 4096 + ij] +
        m1.x * Wc[4 * 4096 + ij] + m1.y * Wc[5 * 4096 + ij] +
        m1.z * Wc[6 * 4096 + ij] + m1.w * Wc[7 * 4096 + ij];

    __shared__ float red[256];
    red[threadIdx.x] = partial;
    __syncthreads();
#pragma unroll
    for (int off = 128; off > 0; off >>= 1) {
        if (threadIdx.x < off) red[threadIdx.x] += red[threadIdx.x + off];
        __syncthreads();
    }
    if (threadIdx.x == 0) atomicAdd(&accum[b], red[0]);
}

__global__ void final_kernel(const float* __restrict__ accum,
                             const float* __restrict__ bc,
                             float* __restrict__ out) {
    int b = threadIdx.x;
    if (b < BB) out[b] = 1.f / (1.f + expf(-(accum[b] + bc[0])));
}

// ---------------------------------------------------------------------------
extern "C" void kernel_launch(void* const* d_in, const int* in_sizes, int n_in,
                              void* d_out, int out_size, void* d_ws, size_t ws_size,
                              hipStream_t stream) {
    const float* x      = (const float*)d_in[0];
    const float* conv_w = (const float*)d_in[1];
    const float* pos_s  = (const float*)d_in[2];
    const float* pos_h  = (const float*)d_in[3];
    const float* pos_w  = (const float*)d_in[4];
    const float* Wq     = (const float*)d_in[5];
    const float* Wkv    = (const float*)d_in[6];
    const float* Wo     = (const float*)d_in[7];
    const float* bo     = (const float*)d_in[8];
    const float* Wc     = (const float*)d_in[9];
    const float* bc     = (const float*)d_in[10];
    float* out = (float*)d_out;

    char* ws = (char*)d_ws;
    float* xt    = (float*)(ws);
    float* zA    = (float*)(ws + ZBYTES);
    float* zB    = (float*)(ws + 2 * ZBYTES);
    float* accum = (float*)(ws + 3 * ZBYTES);

    emb_kernel<<<NPOS / 256, 256, 0, stream>>>(x, conv_w, pos_s, pos_h, pos_w, xt);

    const float* cur = xt;
    float* bufs[2] = {zA, zB};
    int w = 0;
    for (int l = 0; l < NLAYER; ++l) {
        float* dstp = bufs[w];
        const float* wq0  = Wq  + (size_t)(l * 3 + 0) * 128;
        const float* wkv0 = Wkv + (size_t)(l * 3 + 0) * 256;
        const float* wo0  = Wo  + (size_t)(l * 3 + 0) * 128;
        const float* bo0  = bo  + (size_t)(l * 3 + 0) * 8;
        // a=0: attend over s (L=20), RPT=2, 8 lines/block, 320 thr
        attn_kernel<SS, 2, 8, false, 1, 8><<<BB * IMM * IMM / 8, HH * (SS / 2) * 8, 0, stream>>>(
            cur, dstp, wq0, wkv0, wo0, bo0, 8, 64, 512, 32768);
        // a=1: attend over i (L=64), RPT=2, 2 lines/block, 256 thr
        attn_kernel<IMM, 2, 2, true, 1, 8><<<BB * SS * IMM / 2, HH * (IMM / 2) * 2, 0, stream>>>(
            cur, dstp, wq0 + 128, wkv0 + 256, wo0 + 128, bo0 + 8, 8, 20, 32768, 512);
        // a=2: attend over j (L=64), RPT=2, position-fastest staging
        attn_kernel<IMM, 2, 2, true, 0, 8><<<BB * SS * IMM / 2, HH * (IMM / 2) * 2, 0, stream>>>(
            cur, dstp, wq0 + 256, wkv0 + 512, wo0 + 256, bo0 + 16, 512, 20, 32768, 8);
        cur = dstp;
        w ^= 1;
    }

    hipMemsetAsync(accum, 0, BB * sizeof(float), stream);
    reduce_kernel<<<BB * 16, 256, 0, stream>>>(cur, xt, Wc, accum);
    final_kernel<<<1, 64, 0, stream>>>(accum, bc, out);
}

// Round 12
// 444.049 us; speedup vs baseline: 1.1009x; 1.0261x over previous
//
#include <hip/hip_runtime.h>
#include <math.h>

#define DD 8
#define HH 4
#define EE 4
#define NLAYER 4
#define BB 4
#define SS 20
#define IMM 64

static constexpr int NPOS = BB * SS * IMM * IMM;          // 327680
static constexpr size_t ZBYTES = (size_t)NPOS * DD * 4;   // 10485760

// ---------------------------------------------------------------------------
__global__ __launch_bounds__(256)
void emb_kernel(const float* __restrict__ x, const float* __restrict__ conv_w,
                const float* __restrict__ pos_s, const float* __restrict__ pos_h,
                const float* __restrict__ pos_w, float* __restrict__ xt) {
    int idx = blockIdx.x * 256 + threadIdx.x;
    if (idx >= NPOS) return;
    int j = idx & 63;
    int i = (idx >> 6) & 63;
    int s = (idx >> 12) % SS;
    float xv = x[idx];
    float o[8];
#pragma unroll
    for (int d = 0; d < 8; ++d) {
        float v = xv * conv_w[d];
        v = v > 0.f ? v : 0.f;
        o[d] = v + pos_s[s * 8 + d] + pos_h[d * 64 + i] + pos_w[d * 64 + j];
    }
    float4* dst = (float4*)(xt + (size_t)idx * 8);
    dst[0] = make_float4(o[0], o[1], o[2], o[3]);
    dst[1] = make_float4(o[4], o[5], o[6], o[7]);
}

__device__ __forceinline__ float dot4(float4 a, float4 b) {
    return fmaf(a.w, b.w, fmaf(a.z, b.z, fmaf(a.y, b.y, a.x * b.x)));
}
// dot with initial accumulator (folds the -B2 bias into the fma chain)
__device__ __forceinline__ float dot4i(float4 a, float4 b, float c0) {
    return fmaf(a.x, b.x, fmaf(a.y, b.y, fmaf(a.z, b.z, fmaf(a.w, b.w, c0))));
}

// ---------------------------------------------------------------------------
// Axis attention, single-pass softmax with a-priori Cauchy-Schwarz bound
// (p = exp2(q'.k - B2), B2 = |q'|*max|k| in log2 units). RPT=2 query rows
// per thread. zl4/olT4 share one LDS pool (zl4 dead after q-setup; barrier
// guards the transition) so bigger LINES still fits >=3 blocks/CU.
// LINES also sets global coalescing for STG=1: contiguous run = LINES*32B
// (LINES=4 -> 128B = one HBM burst).
template <int L, int RPT, int LINES, bool ACCUM, int STG, int WPE>
__global__ __launch_bounds__(HH * (L / RPT) * LINES, WPE)
void attn_kernel(const float* __restrict__ src, float* __restrict__ dst,
                 const float* __restrict__ Wq, const float* __restrict__ Wkv,
                 const float* __restrict__ Wo, const float* __restrict__ bo,
                 int m0, int c1, int m1, int stride) {
    constexpr int RG = L / RPT;          // row-groups per (line, head)
    constexpr int TL = HH * RG;          // threads per line
    constexpr int NT = TL * LINES;       // block size
    constexpr int LL = L * LINES;

    // pool: phases 1-2 hold zl4[2][LL]; phase 3+ holds olT4[HH][LL]
    __shared__ float4 pool4[HH * LL];
    __shared__ float4 kv4[LL][8];        // quads 0..3 = K heads, 4..7 = V heads
    __shared__ float4 wq4[8][4];         // wq4[d][h]
    __shared__ float4 wkv4[8][8];        // wkv4[d][c]
    __shared__ float4 woq4[16][2];       // woq4[c][dq] = Wo[c][4dq..4dq+3]
    __shared__ float4 bo4_s[2];
    __shared__ float  Mh2[LINES][HH];    // max |k|^2 per (line, head)

#define ZL4(qq, lp)  pool4[(qq) * LL + (lp)]
#define OLT4(hh, lp) pool4[(hh) * LL + (lp)]

    const int t = threadIdx.x;
    if (t < 32) wq4[t >> 2][t & 3]  = *(const float4*)(Wq  + t * 4);
    if (t < 64) wkv4[t >> 3][t & 7] = *(const float4*)(Wkv + t * 4);
    if (t < 32) woq4[t >> 1][t & 1] = *(const float4*)(Wo  + t * 4);
    if (t < 2)  bo4_s[t]            = *(const float4*)(bo  + t * 4);
    if (t < LINES * HH) Mh2[t / HH][t % HH] = 0.f;

    auto line_base = [&](int ln) -> size_t {
        int lid = blockIdx.x * LINES + ln;
        int u0 = lid & 63;
        int rest = lid >> 6;
        int u1 = rest % c1;
        int b  = rest / c1;
        return (size_t)b * 655360 + (size_t)u1 * m1 + (size_t)u0 * m0;
    };
    // (ln, p) mapping for the staging/output iteration order
    auto map_lp = [&](int idx, int& ln, int& p) {
        int r = idx >> 1;
        if (STG == 1) { ln = r % LINES; p = r / LINES; }
        else          { ln = r / L;     p = r % L;     }
    };

    // ---- stage z ----
    for (int idx = t; idx < LL * 2; idx += NT) {
        int ln, p;
        map_lp(idx, ln, p);
        ZL4(idx & 1, ln * L + p) =
            *(const float4*)(src + line_base(ln) + (size_t)p * stride + (idx & 1) * 4);
    }
    __syncthreads();

    // ---- K,V projection (c fixed per thread); track max |k|^2 per head ----
    {
        const int c = t & 7;
        float4 wc[8];
#pragma unroll
        for (int d = 0; d < 8; ++d) wc[d] = wkv4[d][c];
        for (int idx = t; idx < LL * 8; idx += NT) {
            int lp = idx >> 3;
            float4 z0 = ZL4(0, lp), z1 = ZL4(1, lp);
            const float zs[8] = {z0.x, z0.y, z0.z, z0.w, z1.x, z1.y, z1.z, z1.w};
            float4 acc = make_float4(0.f, 0.f, 0.f, 0.f);
#pragma unroll
            for (int d = 0; d < 8; ++d) {
                acc.x += zs[d] * wc[d].x; acc.y += zs[d] * wc[d].y;
                acc.z += zs[d] * wc[d].z; acc.w += zs[d] * wc[d].w;
            }
            kv4[lp][c] = acc;
            if (c < 4)   // K quad: c == head index
                atomicMax((int*)&Mh2[lp / L][c], __float_as_int(dot4(acc, acc)));
        }
    }
    __syncthreads();

    // ---- attention: thread = (line, head, RPT rows); single pass ----
    {
        const int ln = t / TL;
        const int r  = t % TL;
        const int h  = r / RG;
        const int rg = r % RG;
        const int jb = ln * L;
        const int i0 = rg * RPT;
        const float SC = 0.5f * 1.44269504f;   // E^-0.5 * log2(e)

        float4 q[RPT];
        float nB2[RPT];
        const float mh2 = Mh2[ln][h];
#pragma unroll
        for (int k = 0; k < RPT; ++k) {
            float4 z0 = ZL4(0, jb + i0 + k), z1 = ZL4(1, jb + i0 + k);
            const float zs[8] = {z0.x, z0.y, z0.z, z0.w, z1.x, z1.y, z1.z, z1.w};
            float4 acc = make_float4(0.f, 0.f, 0.f, 0.f);
#pragma unroll
            for (int d = 0; d < 8; ++d) {
                float4 w = wq4[d][h];
                acc.x += zs[d] * w.x; acc.y += zs[d] * w.y;
                acc.z += zs[d] * w.z; acc.w += zs[d] * w.w;
            }
            q[k] = make_float4(acc.x * SC, acc.y * SC, acc.z * SC, acc.w * SC);
            nB2[k] = -sqrtf(dot4(q[k], q[k]) * mh2);   // -(|q'| max|k|), log2 units
        }

        // pool transitions zl4 -> olT4: all zl4 reads above must complete
        __syncthreads();

        float s[RPT];
        float4 o[RPT];
#pragma unroll
        for (int k = 0; k < RPT; ++k) { s[k] = 0.f; o[k] = make_float4(0.f, 0.f, 0.f, 0.f); }
#pragma unroll 8
        for (int j = 0; j < L; ++j) {
            float4 kk = kv4[jb + j][h];
            float4 vv = kv4[jb + j][4 + h];
#pragma unroll
            for (int k = 0; k < RPT; ++k) {
                float p = __builtin_amdgcn_exp2f(dot4i(q[k], kk, nB2[k]));
                s[k] += p;
                o[k].x += p * vv.x; o[k].y += p * vv.y;
                o[k].z += p * vv.z; o[k].w += p * vv.w;
            }
        }
#pragma unroll
        for (int k = 0; k < RPT; ++k) {
            const float inv = 1.f / fmaxf(s[k], 1e-37f);
            OLT4(h, jb + i0 + k) =
                make_float4(o[k].x * inv, o[k].y * inv, o[k].z * inv, o[k].w * inv);
        }
    }
    __syncthreads();

    // ---- output projection, float4 per (position, d-quad) ----
    {
        const int dq = t & 1;
        float4 wr[16];
#pragma unroll
        for (int c = 0; c < 16; ++c) wr[c] = woq4[c][dq];
        float4 bo4 = bo4_s[dq];
        for (int idx = t; idx < LL * 2; idx += NT) {
            int ln, p;
            map_lp(idx, ln, p);
            int lp = ln * L + p;
            float4 o0 = OLT4(0, lp), o1 = OLT4(1, lp);
            float4 o2 = OLT4(2, lp), o3 = OLT4(3, lp);
            const float oc[16] = {o0.x, o0.y, o0.z, o0.w, o1.x, o1.y, o1.z, o1.w,
                                  o2.x, o2.y, o2.z, o2.w, o3.x, o3.y, o3.z, o3.w};
            float4 acc = bo4;
#pragma unroll
            for (int c = 0; c < 16; ++c) {
                acc.x += oc[c] * wr[c].x; acc.y += oc[c] * wr[c].y;
                acc.z += oc[c] * wr[c].z; acc.w += oc[c] * wr[c].w;
            }
            float* gp = dst + line_base(ln) + (size_t)p * stride + dq * 4;
            if (ACCUM) {
                float4 old = *(const float4*)gp;
                acc.x += old.x; acc.y += old.y; acc.z += old.z; acc.w += old.w;
            }
            *(float4*)gp = acc;
        }
    }
#undef ZL4
#undef OLT4
}

// ---------------------------------------------------------------------------
__global__ __launch_bounds__(256)
void reduce_kernel(const float* __restrict__ z, const float* __restrict__ xt,
                   const float* __restrict__ Wc, float* __restrict__ accum) {
    const int b  = blockIdx.x >> 4;
    const int ij = ((blockIdx.x & 15) << 8) + threadIdx.x;
    float4 m0 = make_float4(-1e30f, -1e30f, -1e30f, -1e30f);
    float4 m1 = m0;
    for (int s = 0; s < SS; ++s) {
        size_t off = (((size_t)(b * SS + s)) * 4096 + ij) * 8;
        float4 a0 = *(const float4*)(z + off);
        float4 a1 = *(const float4*)(z + off + 4);
        float4 c0 = *(const float4*)(xt + off);
        float4 c1 = *(const float4*)(xt + off + 4);
        m0.x = fmaxf(m0.x, a0.x + c0.x); m0.y = fmaxf(m0.y, a0.y + c0.y);
        m0.z = fmaxf(m0.z, a0.z + c0.z); m0.w = fmaxf(m0.w, a0.w + c0.w);
        m1.x = fmaxf(m1.x, a1.x + c1.x); m1.y = fmaxf(m1.y, a1.y + c1.y);
        m1.z = fmaxf(m1.z, a1.z + c1.z); m1.w = fmaxf(m1.w, a1.w + c1.w);
    }
    float partial =
        m0.x * Wc[0 * 4096 + ij] + m0.y * Wc[1 * 4096 + ij] +
        m0.z * Wc[2 * 4096 + ij] + m0.w * Wc[3 * 4096 + ij] +
        m1.x * Wc[4 * 4096 + ij] + m1.y * Wc[5 * 4096 + ij] +
        m1.z * Wc[6 * 4096 + ij] + m1.w * Wc[7 * 4096 + ij];

    __shared__ float red[256];
    red[threadIdx.x] = partial;
    __syncthreads();
#pragma unroll
    for (int off = 128; off > 0; off >>= 1) {
        if (threadIdx.x < off) red[threadIdx.x] += red[threadIdx.x + off];
        __syncthreads();
    }
    if (threadIdx.x == 0) atomicAdd(&accum[b], red[0]);
}

__global__ void final_kernel(const float* __restrict__ accum,
                             const float* __restrict__ bc,
                             float* __restrict__ out) {
    int b = threadIdx.x;
    if (b < BB) out[b] = 1.f / (1.f + expf(-(accum[b] + bc[0])));
}

// ---------------------------------------------------------------------------
extern "C" void kernel_launch(void* const* d_in, const int* in_sizes, int n_in,
                              void* d_out, int out_size, void* d_ws, size_t ws_size,
                              hipStream_t stream) {
    const float* x      = (const float*)d_in[0];
    const float* conv_w = (const float*)d_in[1];
    const float* pos_s  = (const float*)d_in[2];
    const float* pos_h  = (const float*)d_in[3];
    const float* pos_w  = (const float*)d_in[4];
    const float* Wq     = (const float*)d_in[5];
    const float* Wkv    = (const float*)d_in[6];
    const float* Wo     = (const float*)d_in[7];
    const float* bo     = (const float*)d_in[8];
    const float* Wc     = (const float*)d_in[9];
    const float* bc     = (const float*)d_in[10];
    float* out = (float*)d_out;

    char* ws = (char*)d_ws;
    float* xt    = (float*)(ws);
    float* zA    = (float*)(ws + ZBYTES);
    float* zB    = (float*)(ws + 2 * ZBYTES);
    float* accum = (float*)(ws + 3 * ZBYTES);

    emb_kernel<<<NPOS / 256, 256, 0, stream>>>(x, conv_w, pos_s, pos_h, pos_w, xt);

    const float* cur = xt;
    float* bufs[2] = {zA, zB};
    int w = 0;
    for (int l = 0; l < NLAYER; ++l) {
        float* dstp = bufs[w];
        const float* wq0  = Wq  + (size_t)(l * 3 + 0) * 128;
        const float* wkv0 = Wkv + (size_t)(l * 3 + 0) * 256;
        const float* wo0  = Wo  + (size_t)(l * 3 + 0) * 128;
        const float* bo0  = bo  + (size_t)(l * 3 + 0) * 8;
        // a=0: attend over s (L=20), RPT=2, 8 lines/block, 320 thr
        attn_kernel<SS, 2, 8, false, 1, 8><<<BB * IMM * IMM / 8, HH * (SS / 2) * 8, 0, stream>>>(
            cur, dstp, wq0, wkv0, wo0, bo0, 8, 64, 512, 32768);
        // a=1: attend over i (L=64), RPT=2, 4 lines/block (128B runs), 512 thr
        attn_kernel<IMM, 2, 4, true, 1, 8><<<BB * SS * IMM / 4, HH * (IMM / 2) * 4, 0, stream>>>(
            cur, dstp, wq0 + 128, wkv0 + 256, wo0 + 128, bo0 + 8, 8, 20, 32768, 512);
        // a=2: attend over j (L=64), RPT=2, position-fastest staging (lines contiguous)
        attn_kernel<IMM, 2, 2, true, 0, 8><<<BB * SS * IMM / 2, HH * (IMM / 2) * 2, 0, stream>>>(
            cur, dstp, wq0 + 256, wkv0 + 512, wo0 + 256, bo0 + 16, 512, 20, 32768, 8);
        cur = dstp;
        w ^= 1;
    }

    hipMemsetAsync(accum, 0, BB * sizeof(float), stream);
    reduce_kernel<<<BB * 16, 256, 0, stream>>>(cur, xt, Wc, accum);
    final_kernel<<<1, 64, 0, stream>>>(accum, bc, out);
}

// Round 13
// 438.683 us; speedup vs baseline: 1.1143x; 1.0122x over previous
//
#include <hip/hip_runtime.h>
#include <math.h>

#define DD 8
#define HH 4
#define EE 4
#define NLAYER 4
#define BB 4
#define SS 20
#define IMM 64

static constexpr int NPOS = BB * SS * IMM * IMM;          // 327680
static constexpr size_t ZBYTES = (size_t)NPOS * DD * 4;   // 10485760

__device__ __forceinline__ float dot4(float4 a, float4 b) {
    return fmaf(a.w, b.w, fmaf(a.z, b.z, fmaf(a.y, b.y, a.x * b.x)));
}
// dot with initial accumulator (folds the -B2 bias into the fma chain)
__device__ __forceinline__ float dot4i(float4 a, float4 b, float c0) {
    return fmaf(a.x, b.x, fmaf(a.y, b.y, fmaf(a.z, b.z, fmaf(a.w, b.w, c0))));
}

// ---------------------------------------------------------------------------
// Axis attention, single-pass softmax with a-priori Cauchy-Schwarz bound
// (p = exp2(q'.k - B2), B2 = |q'|*max|k| in log2 units). RPT=2 query rows
// per thread. zl4/olT4 share one LDS pool (zl4 dead after q-setup).
// Geometry (C1, M0, M1, STRIDE) is compile-time: line_base becomes shifts
// (all strides pow2; C1=20 -> magic mul) instead of runtime div/mod.
// EMB=true (layer-0 a=0 only): staging computes relu(x*conv_w)+pos in-reg,
// fills zl4 AND writes xt to global -- fuses the emb kernel and removes a
// 10.5MB strided xt re-read.
template <int L, int RPT, int LINES, bool ACCUM, int STG, int WPE,
          int C1, int M0, int M1, int STRIDE, bool EMB>
__global__ __launch_bounds__(HH * (L / RPT) * LINES, WPE)
void attn_kernel(const float* __restrict__ src, float* __restrict__ dst,
                 const float* __restrict__ Wq, const float* __restrict__ Wkv,
                 const float* __restrict__ Wo, const float* __restrict__ bo,
                 const float* __restrict__ x, const float* __restrict__ conv_w,
                 const float* __restrict__ pos_s, const float* __restrict__ pos_h,
                 const float* __restrict__ pos_w, float* __restrict__ xt_out) {
    constexpr int RG = L / RPT;          // row-groups per (line, head)
    constexpr int TL = HH * RG;          // threads per line
    constexpr int NT = TL * LINES;       // block size
    constexpr int LL = L * LINES;

    // pool: phases 1-2 hold zl4[2][LL]; phase 3+ holds olT4[HH][LL]
    __shared__ float4 pool4[HH * LL];
    __shared__ float4 kv4[LL][8];        // quads 0..3 = K heads, 4..7 = V heads
    __shared__ float4 wq4[8][4];         // wq4[d][h]
    __shared__ float4 wkv4[8][8];        // wkv4[d][c]
    __shared__ float4 woq4[16][2];       // woq4[c][dq] = Wo[c][4dq..4dq+3]
    __shared__ float4 bo4_s[2];
    __shared__ float  Mh2[LINES][HH];    // max |k|^2 per (line, head)

#define ZL4(qq, lp)  pool4[(qq) * LL + (lp)]
#define OLT4(hh, lp) pool4[(hh) * LL + (lp)]

    const int t = threadIdx.x;
    if (t < 32) wq4[t >> 2][t & 3]  = *(const float4*)(Wq  + t * 4);
    if (t < 64) wkv4[t >> 3][t & 7] = *(const float4*)(Wkv + t * 4);
    if (t < 32) woq4[t >> 1][t & 1] = *(const float4*)(Wo  + t * 4);
    if (t < 2)  bo4_s[t]            = *(const float4*)(bo  + t * 4);
    if (t < LINES * HH) Mh2[t / HH][t % HH] = 0.f;

    auto line_coords = [&](int ln, int& u0, int& u1, int& b) {
        int lid = blockIdx.x * LINES + ln;
        u0 = lid & 63;
        int rest = lid >> 6;
        u1 = rest % C1;                  // compile-time C1 -> shift/magic
        b  = rest / C1;
    };
    auto line_base = [&](int ln) -> size_t {
        int u0, u1, b; line_coords(ln, u0, u1, b);
        return (size_t)b * 655360 + (size_t)u1 * M1 + (size_t)u0 * M0;
    };
    // (ln, p) mapping for the staging/output iteration order
    auto map_lp = [&](int idx, int& ln, int& p) {
        int r = idx >> 1;
        if (STG == 1) { ln = r % LINES; p = r / LINES; }
        else          { ln = r / L;     p = r % L;     }
    };

    // ---- stage z (EMB: compute embedding in-register, also write xt) ----
    if constexpr (EMB) {
        __shared__ float cw[8];
        __shared__ float ps[SS * 8];
        __shared__ float ph[8 * IMM];
        __shared__ float pw[8 * IMM];
        if (t < 8) cw[t] = conv_w[t];
        for (int e = t; e < SS * 8; e += NT) ps[e] = pos_s[e];
        for (int e = t; e < 8 * IMM; e += NT) { ph[e] = pos_h[e]; pw[e] = pos_w[e]; }
        __syncthreads();
        for (int lp = t; lp < LL; lp += NT) {
            int ln = lp % LINES, p = lp / LINES;     // ln fastest: consecutive j
            int j, i, b; line_coords(ln, j, i, b);
            float xv = x[(((size_t)b * SS + p) * IMM + i) * IMM + j];
            float o[8];
#pragma unroll
            for (int d = 0; d < 8; ++d) {
                float v = xv * cw[d];
                v = v > 0.f ? v : 0.f;
                o[d] = v + ps[p * 8 + d] + ph[d * IMM + i] + pw[d * IMM + j];
            }
            float4 q0 = make_float4(o[0], o[1], o[2], o[3]);
            float4 q1 = make_float4(o[4], o[5], o[6], o[7]);
            int li = ln * L + p;
            ZL4(0, li) = q0;
            ZL4(1, li) = q1;
            float* gp = xt_out + line_base(ln) + (size_t)p * STRIDE;
            *(float4*)gp = q0;
            *(float4*)(gp + 4) = q1;
        }
    } else {
        for (int idx = t; idx < LL * 2; idx += NT) {
            int ln, p;
            map_lp(idx, ln, p);
            ZL4(idx & 1, ln * L + p) =
                *(const float4*)(src + line_base(ln) + (size_t)p * STRIDE + (idx & 1) * 4);
        }
    }
    __syncthreads();

    // ---- K,V projection (c fixed per thread); track max |k|^2 per head ----
    {
        const int c = t & 7;
        float4 wc[8];
#pragma unroll
        for (int d = 0; d < 8; ++d) wc[d] = wkv4[d][c];
        for (int idx = t; idx < LL * 8; idx += NT) {
            int lp = idx >> 3;
            float4 z0 = ZL4(0, lp), z1 = ZL4(1, lp);
            const float zs[8] = {z0.x, z0.y, z0.z, z0.w, z1.x, z1.y, z1.z, z1.w};
            float4 acc = make_float4(0.f, 0.f, 0.f, 0.f);
#pragma unroll
            for (int d = 0; d < 8; ++d) {
                acc.x += zs[d] * wc[d].x; acc.y += zs[d] * wc[d].y;
                acc.z += zs[d] * wc[d].z; acc.w += zs[d] * wc[d].w;
            }
            kv4[lp][c] = acc;
            if (c < 4)   // K quad: c == head index
                atomicMax((int*)&Mh2[lp / L][c], __float_as_int(dot4(acc, acc)));
        }
    }
    __syncthreads();

    // ---- attention: thread = (line, head, RPT rows); single pass ----
    {
        const int ln = t / TL;
        const int r  = t % TL;
        const int h  = r / RG;
        const int rg = r % RG;
        const int jb = ln * L;
        const int i0 = rg * RPT;
        const float SC = 0.5f * 1.44269504f;   // E^-0.5 * log2(e)

        float4 q[RPT];
        float nB2[RPT];
        const float mh2 = Mh2[ln][h];
#pragma unroll
        for (int k = 0; k < RPT; ++k) {
            float4 z0 = ZL4(0, jb + i0 + k), z1 = ZL4(1, jb + i0 + k);
            const float zs[8] = {z0.x, z0.y, z0.z, z0.w, z1.x, z1.y, z1.z, z1.w};
            float4 acc = make_float4(0.f, 0.f, 0.f, 0.f);
#pragma unroll
            for (int d = 0; d < 8; ++d) {
                float4 w = wq4[d][h];
                acc.x += zs[d] * w.x; acc.y += zs[d] * w.y;
                acc.z += zs[d] * w.z; acc.w += zs[d] * w.w;
            }
            q[k] = make_float4(acc.x * SC, acc.y * SC, acc.z * SC, acc.w * SC);
            nB2[k] = -sqrtf(dot4(q[k], q[k]) * mh2);   // -(|q'| max|k|), log2 units
        }

        // pool transitions zl4 -> olT4: all zl4 reads above must complete
        __syncthreads();

        float s[RPT];
        float4 o[RPT];
#pragma unroll
        for (int k = 0; k < RPT; ++k) { s[k] = 0.f; o[k] = make_float4(0.f, 0.f, 0.f, 0.f); }
#pragma unroll 8
        for (int j = 0; j < L; ++j) {
            float4 kk = kv4[jb + j][h];
            float4 vv = kv4[jb + j][4 + h];
#pragma unroll
            for (int k = 0; k < RPT; ++k) {
                float p = __builtin_amdgcn_exp2f(dot4i(q[k], kk, nB2[k]));
                s[k] += p;
                o[k].x += p * vv.x; o[k].y += p * vv.y;
                o[k].z += p * vv.z; o[k].w += p * vv.w;
            }
        }
#pragma unroll
        for (int k = 0; k < RPT; ++k) {
            const float inv = 1.f / fmaxf(s[k], 1e-37f);
            OLT4(h, jb + i0 + k) =
                make_float4(o[k].x * inv, o[k].y * inv, o[k].z * inv, o[k].w * inv);
        }
    }
    __syncthreads();

    // ---- output projection, float4 per (position, d-quad) ----
    {
        const int dq = t & 1;
        float4 wr[16];
#pragma unroll
        for (int c = 0; c < 16; ++c) wr[c] = woq4[c][dq];
        float4 bo4 = bo4_s[dq];
        for (int idx = t; idx < LL * 2; idx += NT) {
            int ln, p;
            map_lp(idx, ln, p);
            int lp = ln * L + p;
            float4 o0 = OLT4(0, lp), o1 = OLT4(1, lp);
            float4 o2 = OLT4(2, lp), o3 = OLT4(3, lp);
            const float oc[16] = {o0.x, o0.y, o0.z, o0.w, o1.x, o1.y, o1.z, o1.w,
                                  o2.x, o2.y, o2.z, o2.w, o3.x, o3.y, o3.z, o3.w};
            float4 acc = bo4;
#pragma unroll
            for (int c = 0; c < 16; ++c) {
                acc.x += oc[c] * wr[c].x; acc.y += oc[c] * wr[c].y;
                acc.z += oc[c] * wr[c].z; acc.w += oc[c] * wr[c].w;
            }
            float* gp = dst + line_base(ln) + (size_t)p * STRIDE + dq * 4;
            if (ACCUM) {
                float4 old = *(const float4*)gp;
                acc.x += old.x; acc.y += old.y; acc.z += old.z; acc.w += old.w;
            }
            *(float4*)gp = acc;
        }
    }
#undef ZL4
#undef OLT4
}

// ---------------------------------------------------------------------------
__global__ __launch_bounds__(256)
void reduce_kernel(const float* __restrict__ z, const float* __restrict__ xt,
                   const float* __restrict__ Wc, float* __restrict__ accum) {
    const int b  = blockIdx.x >> 4;
    const int ij = ((blockIdx.x & 15) << 8) + threadIdx.x;
    float4 m0 = make_float4(-1e30f, -1e30f, -1e30f, -1e30f);
    float4 m1 = m0;
    for (int s = 0; s < SS; ++s) {
        size_t off = (((size_t)(b * SS + s)) * 4096 + ij) * 8;
        float4 a0 = *(const float4*)(z + off);
        float4 a1 = *(const float4*)(z + off + 4);
        float4 c0 = *(const float4*)(xt + off);
        float4 c1 = *(const float4*)(xt + off + 4);
        m0.x = fmaxf(m0.x, a0.x + c0.x); m0.y = fmaxf(m0.y, a0.y + c0.y);
        m0.z = fmaxf(m0.z, a0.z + c0.z); m0.w = fmaxf(m0.w, a0.w + c0.w);
        m1.x = fmaxf(m1.x, a1.x + c1.x); m1.y = fmaxf(m1.y, a1.y + c1.y);
        m1.z = fmaxf(m1.z, a1.z + c1.z); m1.w = fmaxf(m1.w, a1.w + c1.w);
    }
    float partial =
        m0.x * Wc[0 * 4096 + ij] + m0.y * Wc[1 * 4096 + ij] +
        m0.z * Wc[2 * 4096 + ij] + m0.w * Wc[3 * 4096 + ij] +
        m1.x * Wc[4 * 4096 + ij] + m1.y * Wc[5 * 4096 + ij] +
        m1.z * Wc[6 * 4096 + ij] + m1.w * Wc[7 * 4096 + ij];

    __shared__ float red[256];
    red[threadIdx.x] = partial;
    __syncthreads();
#pragma unroll
    for (int off = 128; off > 0; off >>= 1) {
        if (threadIdx.x < off) red[threadIdx.x] += red[threadIdx.x + off];
        __syncthreads();
    }
    if (threadIdx.x == 0) atomicAdd(&accum[b], red[0]);
}

__global__ void final_kernel(const float* __restrict__ accum,
                             const float* __restrict__ bc,
                             float* __restrict__ out) {
    int b = threadIdx.x;
    if (b < BB) out[b] = 1.f / (1.f + expf(-(accum[b] + bc[0])));
}

// ---------------------------------------------------------------------------
extern "C" void kernel_launch(void* const* d_in, const int* in_sizes, int n_in,
                              void* d_out, int out_size, void* d_ws, size_t ws_size,
                              hipStream_t stream) {
    const float* x      = (const float*)d_in[0];
    const float* conv_w = (const float*)d_in[1];
    const float* pos_s  = (const float*)d_in[2];
    const float* pos_h  = (const float*)d_in[3];
    const float* pos_w  = (const float*)d_in[4];
    const float* Wq     = (const float*)d_in[5];
    const float* Wkv    = (const float*)d_in[6];
    const float* Wo     = (const float*)d_in[7];
    const float* bo     = (const float*)d_in[8];
    const float* Wc     = (const float*)d_in[9];
    const float* bc     = (const float*)d_in[10];
    float* out = (float*)d_out;

    char* ws = (char*)d_ws;
    float* xt    = (float*)(ws);
    float* zA    = (float*)(ws + ZBYTES);
    float* zB    = (float*)(ws + 2 * ZBYTES);
    float* accum = (float*)(ws + 3 * ZBYTES);

    const float* cur = xt;
    float* bufs[2] = {zA, zB};
    int w = 0;
    for (int l = 0; l < NLAYER; ++l) {
        float* dstp = bufs[w];
        const float* wq0  = Wq  + (size_t)(l * 3 + 0) * 128;
        const float* wkv0 = Wkv + (size_t)(l * 3 + 0) * 256;
        const float* wo0  = Wo  + (size_t)(l * 3 + 0) * 128;
        const float* bo0  = bo  + (size_t)(l * 3 + 0) * 8;
        // a=0: attend over s (L=20), RPT=2, 8 lines/block, 320 thr.
        // Layer 0 fuses the embedding (computes xt in-staging, writes it out).
        if (l == 0) {
            attn_kernel<SS, 2, 8, false, 1, 8, 64, 8, 512, 32768, true>
                <<<BB * IMM * IMM / 8, HH * (SS / 2) * 8, 0, stream>>>(
                xt, dstp, wq0, wkv0, wo0, bo0, x, conv_w, pos_s, pos_h, pos_w, xt);
        } else {
            attn_kernel<SS, 2, 8, false, 1, 8, 64, 8, 512, 32768, false>
                <<<BB * IMM * IMM / 8, HH * (SS / 2) * 8, 0, stream>>>(
                cur, dstp, wq0, wkv0, wo0, bo0,
                nullptr, nullptr, nullptr, nullptr, nullptr, nullptr);
        }
        // a=1: attend over i (L=64), RPT=2, 4 lines/block (128B runs), 512 thr
        attn_kernel<IMM, 2, 4, true, 1, 8, 20, 8, 32768, 512, false>
            <<<BB * SS * IMM / 4, HH * (IMM / 2) * 4, 0, stream>>>(
            cur, dstp, wq0 + 128, wkv0 + 256, wo0 + 128, bo0 + 8,
            nullptr, nullptr, nullptr, nullptr, nullptr, nullptr);
        // a=2: attend over j (L=64), RPT=2, position-fastest staging
        attn_kernel<IMM, 2, 2, true, 0, 8, 20, 512, 32768, 8, false>
            <<<BB * SS * IMM / 2, HH * (IMM / 2) * 2, 0, stream>>>(
            cur, dstp, wq0 + 256, wkv0 + 512, wo0 + 256, bo0 + 16,
            nullptr, nullptr, nullptr, nullptr, nullptr, nullptr);
        cur = dstp;
        w ^= 1;
    }

    hipMemsetAsync(accum, 0, BB * sizeof(float), stream);
    reduce_kernel<<<BB * 16, 256, 0, stream>>>(cur, xt, Wc, accum);
    final_kernel<<<1, 64, 0, stream>>>(accum, bc, out);
}

// Round 14
// 412.947 us; speedup vs baseline: 1.1838x; 1.0623x over previous
//
#include <hip/hip_runtime.h>
#include <math.h>

#define DD 8
#define HH 4
#define NLAYER 4
#define BB 4
#define SS 20
#define IMM 64

static constexpr int NPOS = BB * SS * IMM * IMM;          // 327680
static constexpr size_t ZBYTES = (size_t)NPOS * DD * 4;   // 10485760

__device__ __forceinline__ float dot4(float4 a, float4 b) {
    return fmaf(a.w, b.w, fmaf(a.z, b.z, fmaf(a.y, b.y, a.x * b.x)));
}
// dot with initial accumulator (folds the -B2 bias into the fma chain)
__device__ __forceinline__ float dot4i(float4 a, float4 b, float c0) {
    return fmaf(a.x, b.x, fmaf(a.y, b.y, fmaf(a.z, b.z, fmaf(a.w, b.w, c0))));
}

// ---------------------------------------------------------------------------
template <int LL, int LINES, bool EMB>
struct Smem {
    float4 pool4[4 * LL];        // phases 1-2: zl4[2][LL]; phase 3+: olT4[HH][LL]
    float4 kv4[LL][8];           // quads 0..3 = K heads, 4..7 = V heads
    float4 wq4[8][4];
    float4 wkv4[8][8];
    float4 woq4[16][2];
    float4 bo4_s[2];
    float  Mh2[LINES][HH];       // max |k|^2 per (line, head)
    float  embtab[EMB ? (8 + SS * 8 + 2 * 8 * IMM) : 1];
};

// Axis attention phase (device fn). Single-pass softmax with Cauchy-Schwarz
// bound (p = exp2(q'.k - B2)); RPT=2 rows/thread; zl4/olT4 share pool.
// AXIS fixes geometry at compile time. EMB: staging computes
// relu(x*conv_w)+pos in-register (XTW additionally writes xt).
// SUM3: epilogue adds add1+add2 (same thread reads before writing dst, so
// dst may alias add1). ACCUM: legacy read-modify-write (fallback path).
template <int AXIS, int L, int RPT, int LINES, int STG, int NT,
          bool EMB, bool XTW, bool SUM3, bool ACCUM, typename SM>
__device__ __forceinline__ void axial_phase(
    SM& sm, int lid0,
    const float* __restrict__ src,
    const float* __restrict__ add1, const float* __restrict__ add2,
    float* __restrict__ dst,
    const float* __restrict__ Wq, const float* __restrict__ Wkv,
    const float* __restrict__ Wo, const float* __restrict__ bo,
    const float* __restrict__ x, const float* __restrict__ conv_w,
    const float* __restrict__ pos_s, const float* __restrict__ pos_h,
    const float* __restrict__ pos_w, float* __restrict__ xt_out)
{
    constexpr int RG = L / RPT;
    constexpr int TL = HH * RG;
    constexpr int LL = L * LINES;
    constexpr int C1 = (AXIS == 0) ? 64 : 20;
    constexpr int M0 = (AXIS == 2) ? 512 : 8;
    constexpr int M1 = (AXIS == 0) ? 512 : 32768;
    constexpr int STRIDE = (AXIS == 0) ? 32768 : ((AXIS == 1) ? 512 : 8);

    const int t = threadIdx.x;
    if (t < 32) sm.wq4[t >> 2][t & 3]  = *(const float4*)(Wq  + t * 4);
    if (t < 64) sm.wkv4[t >> 3][t & 7] = *(const float4*)(Wkv + t * 4);
    if (t < 32) sm.woq4[t >> 1][t & 1] = *(const float4*)(Wo  + t * 4);
    if (t < 2)  sm.bo4_s[t]            = *(const float4*)(bo  + t * 4);
    if (t < LINES * HH) sm.Mh2[t / HH][t % HH] = 0.f;

    auto coords = [&](int ln, int& u0, int& u1, int& b) {
        int lid = lid0 + ln;
        u0 = lid & 63;
        int rest = lid >> 6;
        u1 = rest % C1;
        b  = rest / C1;
    };
    auto line_base = [&](int ln) -> size_t {
        int u0, u1, b; coords(ln, u0, u1, b);
        return (size_t)b * 655360 + (size_t)u1 * M1 + (size_t)u0 * M0;
    };
    auto map_r = [&](int r, int& ln, int& p) {
        if (STG == 1) { ln = r % LINES; p = r / LINES; }
        else          { ln = r / L;     p = r % L;     }
    };

#define ZL4_(qq, lp)  sm.pool4[(qq) * LL + (lp)]
#define OLT4_(hh, lp) sm.pool4[(hh) * LL + (lp)]

    // ---- stage z ----
    if constexpr (EMB) {
        float* cw = sm.embtab;
        float* ps = cw + 8;
        float* ph = ps + SS * 8;
        float* pw = ph + 8 * IMM;
        if (t < 8) cw[t] = conv_w[t];
        for (int e = t; e < SS * 8; e += NT) ps[e] = pos_s[e];
        for (int e = t; e < 8 * IMM; e += NT) { ph[e] = pos_h[e]; pw[e] = pos_w[e]; }
        __syncthreads();
        for (int lp = t; lp < LL; lp += NT) {
            int ln, p; map_r(lp, ln, p);
            int u0, u1, b; coords(ln, u0, u1, b);
            size_t zb = (size_t)b * 655360 + (size_t)u1 * M1 + (size_t)u0 * M0
                      + (size_t)p * STRIDE;
            float xv = x[zb >> 3];
            int si = (AXIS == 0) ? p : u1;
            int ii = (AXIS == 0) ? u1 : ((AXIS == 1) ? p : u0);
            int ji = (AXIS == 2) ? p : u0;
            float o[8];
#pragma unroll
            for (int d = 0; d < 8; ++d) {
                float v = xv * cw[d];
                v = v > 0.f ? v : 0.f;
                o[d] = v + ps[si * 8 + d] + ph[d * IMM + ii] + pw[d * IMM + ji];
            }
            float4 q0 = make_float4(o[0], o[1], o[2], o[3]);
            float4 q1 = make_float4(o[4], o[5], o[6], o[7]);
            int li = ln * L + p;
            ZL4_(0, li) = q0;
            ZL4_(1, li) = q1;
            if constexpr (XTW) {
                *(float4*)(xt_out + zb)     = q0;
                *(float4*)(xt_out + zb + 4) = q1;
            }
        }
    } else {
        for (int idx = t; idx < LL * 2; idx += NT) {
            int ln, p; map_r(idx >> 1, ln, p);
            ZL4_(idx & 1, ln * L + p) =
                *(const float4*)(src + line_base(ln) + (size_t)p * STRIDE + (idx & 1) * 4);
        }
    }
    __syncthreads();

    // ---- K,V projection (c fixed per thread); track max |k|^2 per head ----
    {
        const int c = t & 7;
        float4 wc[8];
#pragma unroll
        for (int d = 0; d < 8; ++d) wc[d] = sm.wkv4[d][c];
        for (int idx = t; idx < LL * 8; idx += NT) {
            int lp = idx >> 3;
            float4 z0 = ZL4_(0, lp), z1 = ZL4_(1, lp);
            const float zs[8] = {z0.x, z0.y, z0.z, z0.w, z1.x, z1.y, z1.z, z1.w};
            float4 acc = make_float4(0.f, 0.f, 0.f, 0.f);
#pragma unroll
            for (int d = 0; d < 8; ++d) {
                acc.x += zs[d] * wc[d].x; acc.y += zs[d] * wc[d].y;
                acc.z += zs[d] * wc[d].z; acc.w += zs[d] * wc[d].w;
            }
            sm.kv4[lp][c] = acc;
            if (c < 4)
                atomicMax((int*)&sm.Mh2[lp / L][c], __float_as_int(dot4(acc, acc)));
        }
    }
    __syncthreads();

    // ---- attention: thread = (line, head, RPT rows); single pass ----
    {
        const int ln = t / TL;
        const int r  = t % TL;
        const int h  = r / RG;
        const int rg = r % RG;
        const int jb = ln * L;
        const int i0 = rg * RPT;
        const float SC = 0.5f * 1.44269504f;   // E^-0.5 * log2(e)

        float4 q[RPT];
        float nB2[RPT];
        const float mh2 = sm.Mh2[ln][h];
#pragma unroll
        for (int k = 0; k < RPT; ++k) {
            float4 z0 = ZL4_(0, jb + i0 + k), z1 = ZL4_(1, jb + i0 + k);
            const float zs[8] = {z0.x, z0.y, z0.z, z0.w, z1.x, z1.y, z1.z, z1.w};
            float4 acc = make_float4(0.f, 0.f, 0.f, 0.f);
#pragma unroll
            for (int d = 0; d < 8; ++d) {
                float4 w = sm.wq4[d][h];
                acc.x += zs[d] * w.x; acc.y += zs[d] * w.y;
                acc.z += zs[d] * w.z; acc.w += zs[d] * w.w;
            }
            q[k] = make_float4(acc.x * SC, acc.y * SC, acc.z * SC, acc.w * SC);
            nB2[k] = -sqrtf(dot4(q[k], q[k]) * mh2);
        }

        // pool transitions zl4 -> olT4: all zl4 reads above must complete
        __syncthreads();

        float s[RPT];
        float4 o[RPT];
#pragma unroll
        for (int k = 0; k < RPT; ++k) { s[k] = 0.f; o[k] = make_float4(0.f, 0.f, 0.f, 0.f); }
#pragma unroll 8
        for (int j = 0; j < L; ++j) {
            float4 kk = sm.kv4[jb + j][h];
            float4 vv = sm.kv4[jb + j][4 + h];
#pragma unroll
            for (int k = 0; k < RPT; ++k) {
                float p = __builtin_amdgcn_exp2f(dot4i(q[k], kk, nB2[k]));
                s[k] += p;
                o[k].x += p * vv.x; o[k].y += p * vv.y;
                o[k].z += p * vv.z; o[k].w += p * vv.w;
            }
        }
#pragma unroll
        for (int k = 0; k < RPT; ++k) {
            const float inv = 1.f / fmaxf(s[k], 1e-37f);
            OLT4_(h, jb + i0 + k) =
                make_float4(o[k].x * inv, o[k].y * inv, o[k].z * inv, o[k].w * inv);
        }
    }
    __syncthreads();

    // ---- output projection ----
    {
        const int dq = t & 1;
        float4 wr[16];
#pragma unroll
        for (int c = 0; c < 16; ++c) wr[c] = sm.woq4[c][dq];
        float4 bo4 = sm.bo4_s[dq];
        for (int idx = t; idx < LL * 2; idx += NT) {
            int ln, p; map_r(idx >> 1, ln, p);
            int lp = ln * L + p;
            float4 o0 = OLT4_(0, lp), o1 = OLT4_(1, lp);
            float4 o2 = OLT4_(2, lp), o3 = OLT4_(3, lp);
            const float oc[16] = {o0.x, o0.y, o0.z, o0.w, o1.x, o1.y, o1.z, o1.w,
                                  o2.x, o2.y, o2.z, o2.w, o3.x, o3.y, o3.z, o3.w};
            float4 acc = bo4;
#pragma unroll
            for (int c = 0; c < 16; ++c) {
                acc.x += oc[c] * wr[c].x; acc.y += oc[c] * wr[c].y;
                acc.z += oc[c] * wr[c].z; acc.w += oc[c] * wr[c].w;
            }
            size_t g = line_base(ln) + (size_t)p * STRIDE + dq * 4;
            if constexpr (SUM3) {
                float4 a1v = *(const float4*)(add1 + g);
                float4 a2v = *(const float4*)(add2 + g);
                acc.x += a1v.x; acc.y += a1v.y; acc.z += a1v.z; acc.w += a1v.w;
                acc.x += a2v.x; acc.y += a2v.y; acc.z += a2v.z; acc.w += a2v.w;
            }
            if constexpr (ACCUM) {
                float4 old = *(const float4*)(dst + g);
                acc.x += old.x; acc.y += old.y; acc.z += old.z; acc.w += old.w;
            }
            *(float4*)(dst + g) = acc;
        }
    }
#undef ZL4_
#undef OLT4_
}

// ---------------------------------------------------------------------------
// D1: a=1 and a=2 merged into one dispatch (independent: both read src only,
// each writes its own buffer). 5120 blocks -> ~2x deeper grid, smaller tail.
template <bool EMB>
__global__ __launch_bounds__(256, 8)
void d1_kernel(const float* __restrict__ src, float* __restrict__ o1,
               float* __restrict__ o2,
               const float* __restrict__ Wq, const float* __restrict__ Wkv,
               const float* __restrict__ Wo, const float* __restrict__ bo,
               const float* __restrict__ x, const float* __restrict__ conv_w,
               const float* __restrict__ pos_s, const float* __restrict__ pos_h,
               const float* __restrict__ pos_w) {
    __shared__ Smem<128, 2, EMB> sm;
    const int bid = blockIdx.x;
    if (bid < 2560) {
        axial_phase<1, 64, 2, 2, 1, 256, EMB, false, false, false>(
            sm, bid * 2, src, nullptr, nullptr, o1,
            Wq + 128, Wkv + 256, Wo + 128, bo + 8,
            x, conv_w, pos_s, pos_h, pos_w, nullptr);
    } else {
        axial_phase<2, 64, 2, 2, 0, 256, EMB, false, false, false>(
            sm, (bid - 2560) * 2, src, nullptr, nullptr, o2,
            Wq + 256, Wkv + 512, Wo + 256, bo + 16,
            x, conv_w, pos_s, pos_h, pos_w, nullptr);
    }
}

// D2: a=0; epilogue sums attn0+bo + o1 + o2 (dst may alias o1: same-thread
// read-then-write). EMB also writes xt.
template <bool EMB, bool SUM3, bool ACCUM>
__global__ __launch_bounds__(320, 8)
void d2_kernel(const float* __restrict__ src, const float* __restrict__ add1,
               const float* __restrict__ add2, float* __restrict__ dst,
               const float* __restrict__ Wq, const float* __restrict__ Wkv,
               const float* __restrict__ Wo, const float* __restrict__ bo,
               const float* __restrict__ x, const float* __restrict__ conv_w,
               const float* __restrict__ pos_s, const float* __restrict__ pos_h,
               const float* __restrict__ pos_w, float* __restrict__ xt_out) {
    __shared__ Smem<160, 8, EMB> sm;
    axial_phase<0, 20, 2, 8, 1, 320, EMB, EMB, SUM3, ACCUM>(
        sm, blockIdx.x * 8, src, add1, add2, dst,
        Wq, Wkv, Wo, bo, x, conv_w, pos_s, pos_h, pos_w, xt_out);
}

// Fallback-path a=1 / a=2 kernels (legacy ACCUM rmw), used if ws too small.
__global__ __launch_bounds__(512, 8)
void a1_fb_kernel(const float* __restrict__ src, float* __restrict__ dst,
                  const float* __restrict__ Wq, const float* __restrict__ Wkv,
                  const float* __restrict__ Wo, const float* __restrict__ bo) {
    __shared__ Smem<256, 4, false> sm;
    axial_phase<1, 64, 2, 4, 1, 512, false, false, false, true>(
        sm, blockIdx.x * 4, src, nullptr, nullptr, dst,
        Wq + 128, Wkv + 256, Wo + 128, bo + 8,
        nullptr, nullptr, nullptr, nullptr, nullptr, nullptr);
}
__global__ __launch_bounds__(256, 8)
void a2_fb_kernel(const float* __restrict__ src, float* __restrict__ dst,
                  const float* __restrict__ Wq, const float* __restrict__ Wkv,
                  const float* __restrict__ Wo, const float* __restrict__ bo) {
    __shared__ Smem<128, 2, false> sm;
    axial_phase<2, 64, 2, 2, 0, 256, false, false, false, true>(
        sm, blockIdx.x * 2, src, nullptr, nullptr, dst,
        Wq + 256, Wkv + 512, Wo + 256, bo + 16,
        nullptr, nullptr, nullptr, nullptr, nullptr, nullptr);
}

// ---------------------------------------------------------------------------
__global__ __launch_bounds__(256)
void reduce_kernel(const float* __restrict__ z, const float* __restrict__ xt,
                   const float* __restrict__ Wc, float* __restrict__ accum) {
    const int b  = blockIdx.x >> 4;
    const int ij = ((blockIdx.x & 15) << 8) + threadIdx.x;
    float4 m0 = make_float4(-1e30f, -1e30f, -1e30f, -1e30f);
    float4 m1 = m0;
    for (int s = 0; s < SS; ++s) {
        size_t off = (((size_t)(b * SS + s)) * 4096 + ij) * 8;
        float4 a0 = *(const float4*)(z + off);
        float4 a1 = *(const float4*)(z + off + 4);
        float4 c0 = *(const float4*)(xt + off);
        float4 c1 = *(const float4*)(xt + off + 4);
        m0.x = fmaxf(m0.x, a0.x + c0.x); m0.y = fmaxf(m0.y, a0.y + c0.y);
        m0.z = fmaxf(m0.z, a0.z + c0.z); m0.w = fmaxf(m0.w, a0.w + c0.w);
        m1.x = fmaxf(m1.x, a1.x + c1.x); m1.y = fmaxf(m1.y, a1.y + c1.y);
        m1.z = fmaxf(m1.z, a1.z + c1.z); m1.w = fmaxf(m1.w, a1.w + c1.w);
    }
    float partial =
        m0.x * Wc[0 * 4096 + ij] + m0.y * Wc[1 * 4096 + ij] +
        m0.z * Wc[2 * 4096 + ij] + m0.w * Wc[3 * 4096 + ij] +
        m1.x * Wc[4 * 4096 + ij] + m1.y * Wc[5 * 4096 + ij] +
        m1.z * Wc[6 * 4096 + ij] + m1.w * Wc[7 * 4096 + ij];

    __shared__ float red[256];
    red[threadIdx.x] = partial;
    __syncthreads();
#pragma unroll
    for (int off = 128; off > 0; off >>= 1) {
        if (threadIdx.x < off) red[threadIdx.x] += red[threadIdx.x + off];
        __syncthreads();
    }
    if (threadIdx.x == 0) atomicAdd(&accum[b], red[0]);
}

__global__ void final_kernel(const float* __restrict__ accum,
                             const float* __restrict__ bc,
                             float* __restrict__ out) {
    int b = threadIdx.x;
    if (b < BB) out[b] = 1.f / (1.f + expf(-(accum[b] + bc[0])));
}

// ---------------------------------------------------------------------------
extern "C" void kernel_launch(void* const* d_in, const int* in_sizes, int n_in,
                              void* d_out, int out_size, void* d_ws, size_t ws_size,
                              hipStream_t stream) {
    const float* x      = (const float*)d_in[0];
    const float* conv_w = (const float*)d_in[1];
    const float* pos_s  = (const float*)d_in[2];
    const float* pos_h  = (const float*)d_in[3];
    const float* pos_w  = (const float*)d_in[4];
    const float* Wq     = (const float*)d_in[5];
    const float* Wkv    = (const float*)d_in[6];
    const float* Wo     = (const float*)d_in[7];
    const float* bo     = (const float*)d_in[8];
    const float* Wc     = (const float*)d_in[9];
    const float* bc     = (const float*)d_in[10];
    float* out = (float*)d_out;

    char* ws = (char*)d_ws;
    const bool big = ws_size >= 4 * ZBYTES + 256;

    const float* zfinal;
    float* xt = (float*)ws;
    float* accum;

    if (big) {
        float* A = (float*)(ws + ZBYTES);
        float* B = (float*)(ws + 2 * ZBYTES);
        float* C = (float*)(ws + 3 * ZBYTES);
        accum    = (float*)(ws + 4 * ZBYTES);
        float* zc[4] = {nullptr, A, B, A};       // layer inputs (L0 = emb)
        float* o1[4] = {B, B, A, B};
        float* o2[4] = {C, C, C, C};
        float* zn[4] = {A, B, A, B};             // layer outputs (zn==o1 for l>0)
        for (int l = 0; l < NLAYER; ++l) {
            const float* wq0  = Wq  + (size_t)(l * 3) * 128;
            const float* wkv0 = Wkv + (size_t)(l * 3) * 256;
            const float* wo0  = Wo  + (size_t)(l * 3) * 128;
            const float* bo0  = bo  + (size_t)(l * 3) * 8;
            if (l == 0) {
                d1_kernel<true><<<5120, 256, 0, stream>>>(
                    nullptr, o1[0], o2[0], wq0, wkv0, wo0, bo0,
                    x, conv_w, pos_s, pos_h, pos_w);
                d2_kernel<true, true, false><<<2048, 320, 0, stream>>>(
                    nullptr, o1[0], o2[0], zn[0], wq0, wkv0, wo0, bo0,
                    x, conv_w, pos_s, pos_h, pos_w, xt);
            } else {
                d1_kernel<false><<<5120, 256, 0, stream>>>(
                    zc[l], o1[l], o2[l], wq0, wkv0, wo0, bo0,
                    nullptr, nullptr, nullptr, nullptr, nullptr);
                d2_kernel<false, true, false><<<2048, 320, 0, stream>>>(
                    zc[l], o1[l], o2[l], zn[l], wq0, wkv0, wo0, bo0,
                    nullptr, nullptr, nullptr, nullptr, nullptr, nullptr);
            }
        }
        zfinal = zn[3];
    } else {
        // fallback: R12 flow (xt, zA, zB ping-pong; a1/a2 rmw-accumulate)
        float* zA = (float*)(ws + ZBYTES);
        float* zB = (float*)(ws + 2 * ZBYTES);
        accum     = (float*)(ws + 3 * ZBYTES);
        const float* cur = xt;
        float* bufs[2] = {zA, zB};
        int w = 0;
        for (int l = 0; l < NLAYER; ++l) {
            float* dstp = bufs[w];
            const float* wq0  = Wq  + (size_t)(l * 3) * 128;
            const float* wkv0 = Wkv + (size_t)(l * 3) * 256;
            const float* wo0  = Wo  + (size_t)(l * 3) * 128;
            const float* bo0  = bo  + (size_t)(l * 3) * 8;
            if (l == 0) {
                d2_kernel<true, false, false><<<2048, 320, 0, stream>>>(
                    xt, nullptr, nullptr, dstp, wq0, wkv0, wo0, bo0,
                    x, conv_w, pos_s, pos_h, pos_w, xt);
            } else {
                d2_kernel<false, false, false><<<2048, 320, 0, stream>>>(
                    cur, nullptr, nullptr, dstp, wq0, wkv0, wo0, bo0,
                    nullptr, nullptr, nullptr, nullptr, nullptr, nullptr);
            }
            a1_fb_kernel<<<1280, 512, 0, stream>>>(cur, dstp, wq0, wkv0, wo0, bo0);
            a2_fb_kernel<<<2560, 256, 0, stream>>>(cur, dstp, wq0, wkv0, wo0, bo0);
            cur = dstp;
            w ^= 1;
        }
        zfinal = cur;
    }

    hipMemsetAsync(accum, 0, BB * sizeof(float), stream);
    reduce_kernel<<<BB * 16, 256, 0, stream>>>(zfinal, xt, Wc, accum);
    final_kernel<<<1, 64, 0, stream>>>(accum, bc, out);
}